// Round 1
// baseline (4507.384 us; speedup 1.0000x reference)
//
#include <hip/hip_runtime.h>
#include <hip/hip_fp16.h>
#include <hip/hip_bf16.h>

// ---------------------------------------------------------------------------
// HAConvGNN forward. fp32 compute; GRU recurrent weights cached in registers
// as f16 (hfma2 dots, f32 flush every 8 pairs).
// ---------------------------------------------------------------------------

// ---------------- generic fp32 tiled GEMM ----------------------------------
// C[M,N] = A(@rows, maybe gathered)[M,K] * B + bias, optional relu,
// batched via z = (s,b) decomposition, optional atomic split-K.
// BT: B stored [N,K] (C = A*B^T). !BT: B stored [K,N].
template <bool BT, bool RELU, bool GATHER, bool ATOMIC>
__global__ __launch_bounds__(256) void k_gemm(
    const float* __restrict__ A, long lda, long a_ss, long a_sb,
    const float* __restrict__ B, long ldb, long b_ss, long b_sb,
    float* __restrict__ C, long ldc, long c_ss, long c_sb,
    const float* __restrict__ bias, long bias_ss,
    const int* __restrict__ gidx,
    int M, int N, int K, int zb, int ksplit)
{
  __shared__ float As[16][68];
  __shared__ float Bs[16][68];
  const int tid = threadIdx.x;
  const int zi = blockIdx.z;
  const int bi = zi / ksplit;
  const int ks = zi - bi * ksplit;
  const int sIdx = bi / zb;
  const int bIdx = bi - sIdx * zb;
  const int row0 = blockIdx.y * 64;
  const int col0 = blockIdx.x * 64;
  const int Kc = (K + ksplit - 1) / ksplit;
  const int kbeg = ks * Kc;
  const int kend = min(K, kbeg + Kc);

  const float* Ab = A + (long)sIdx * a_ss + (long)bIdx * a_sb;
  const float* Bb = B + (long)sIdx * b_ss + (long)bIdx * b_sb;
  float* Cb = C + (long)sIdx * c_ss + (long)bIdx * c_sb;

  const int tx = tid & 15, ty = tid >> 4;
  float acc[4][4];
#pragma unroll
  for (int i = 0; i < 4; ++i)
#pragma unroll
    for (int j = 0; j < 4; ++j) acc[i][j] = 0.f;

  // A tile load mapping: 64 rows x 16 k, 4 elems/thread
  const int ar = tid >> 2;
  const int ac = (tid & 3) * 4;
  const int am = row0 + ar;
  const bool amok = am < M;
  const float* arow;
  if (GATHER) arow = A + (amok ? (long)gidx[am] * lda : 0);
  else        arow = Ab + (long)am * lda;

  for (int kt = kbeg; kt < kend; kt += 16) {
#pragma unroll
    for (int j = 0; j < 4; ++j) {
      const int kk = kt + ac + j;
      As[ac + j][ar] = (amok && kk < kend) ? arow[kk] : 0.f;
    }
    if (BT) {
      const int br = tid >> 2;            // n-local
      const int bc = (tid & 3) * 4;       // k-local
      const int nn = col0 + br;
      const bool bok = nn < N;
      const float* brow = Bb + (long)nn * ldb;
#pragma unroll
      for (int j = 0; j < 4; ++j) {
        const int kk = kt + bc + j;
        Bs[bc + j][br] = (bok && kk < kend) ? brow[kk] : 0.f;
      }
    } else {
      const int br = tid >> 4;            // k-local
      const int bc = (tid & 15) * 4;      // n-local
      const int kk = kt + br;
      const float* brow = Bb + (long)kk * ldb;
#pragma unroll
      for (int j = 0; j < 4; ++j) {
        const int nn = col0 + bc + j;
        Bs[br][bc + j] = (kk < kend && nn < N) ? brow[nn] : 0.f;
      }
    }
    __syncthreads();
#pragma unroll
    for (int kk = 0; kk < 16; ++kk) {
      const float4 av = *(const float4*)&As[kk][ty * 4];
      const float4 bv = *(const float4*)&Bs[kk][tx * 4];
      const float aa[4] = {av.x, av.y, av.z, av.w};
      const float bb[4] = {bv.x, bv.y, bv.z, bv.w};
#pragma unroll
      for (int i = 0; i < 4; ++i)
#pragma unroll
        for (int j = 0; j < 4; ++j)
          acc[i][j] = fmaf(aa[i], bb[j], acc[i][j]);
    }
    __syncthreads();
  }

  const float* biasp = bias ? bias + (long)sIdx * bias_ss : nullptr;
#pragma unroll
  for (int i = 0; i < 4; ++i) {
    const int m = row0 + ty * 4 + i;
    if (m >= M) continue;
    float* crow = Cb + (long)m * ldc;
#pragma unroll
    for (int j = 0; j < 4; ++j) {
      const int n = col0 + tx * 4 + j;
      if (n >= N) continue;
      if (ATOMIC) {
        atomicAdd(&crow[n], acc[i][j]);
      } else {
        float v = acc[i][j];
        if (biasp) v += biasp[n];
        if (RELU) v = fmaxf(v, 0.f);
        crow[n] = v;
      }
    }
  }
}

// ---------------- C[M,N] = bias[N] (init for atomic split-K) ---------------
__global__ __launch_bounds__(256) void k_init_bias(
    float* __restrict__ C, const float* __restrict__ bias, int M, int N)
{
  const int total = M * N;
  for (int i = blockIdx.x * 256 + threadIdx.x; i < total; i += gridDim.x * 256)
    C[i] = bias[i % N];
}

// ---------------- astwork[s][b][n][d] = emb_ast[x2[b][s][n]][d] ------------
__global__ __launch_bounds__(256) void k_gather_ast(
    const float* __restrict__ emb, const int* __restrict__ x2,
    float* __restrict__ outp)
{
  const int total = 4 * 32 * 300 * 300;
  for (int idx = blockIdx.x * 256 + threadIdx.x; idx < total; idx += gridDim.x * 256) {
    const int d = idx % 300;
    const int r = idx / 300;
    const int n = r % 300;
    const int r2 = r / 300;
    const int b = r2 % 32;
    const int s = r2 / 32;
    outp[idx] = emb[(long)x2[(b * 4 + s) * 300 + n] * 300 + d];
  }
}

// ---------------- GRU sequence: one block per independent chain ------------
// xg [C][T][768] precomputed (incl. bih). whh cached in regs as f16.
// Thread t: unit j = t>>1 owns K-half kh = t&1 (128 of 256).
__global__ __launch_bounds__(512) void k_gru_seq(
    const float* __restrict__ xg,
    const float* __restrict__ h0, int h0_mod,
    const float* __restrict__ whh, long w_stride, int cpw,
    const float* __restrict__ bhh, long b_stride,
    float* __restrict__ ys, float* __restrict__ hT, int T)
{
  const int c = blockIdx.x;
  const int tid = threadIdx.x;
  const int j = tid >> 1;
  const int kh = tid & 1;
  const int w = c / cpw;
  const float* W = whh + (long)w * w_stride;
  const float* Bh = bhh + (long)w * b_stride;

  __half2 wr[64], wz[64], wn[64];
  {
    const float* pr = W + (long)j * 256 + kh * 128;
    const float* pz = W + (long)(j + 256) * 256 + kh * 128;
    const float* pn = W + (long)(j + 512) * 256 + kh * 128;
#pragma unroll
    for (int i = 0; i < 64; ++i) {
      wr[i] = __floats2half2_rn(pr[2 * i], pr[2 * i + 1]);
      wz[i] = __floats2half2_rn(pz[2 * i], pz[2 * i + 1]);
      wn[i] = __floats2half2_rn(pn[2 * i], pn[2 * i + 1]);
    }
  }
  const float br = Bh[j], bz = Bh[256 + j], bn = Bh[512 + j];

  __shared__ float  h32[2][256];
  __shared__ __half h16[2][256];
  if (kh == 0) {
    const float hv = h0 ? h0[(long)(c % h0_mod) * 256 + j] : 0.f;
    h32[0][j] = hv;
    h16[0][j] = __float2half(hv);
  }
  __syncthreads();

  const float* xrow = xg + (long)c * T * 768;
  float* yrow = ys ? ys + (long)c * T * 256 : nullptr;
  int cur = 0;
  for (int t = 0; t < T; ++t) {
    const __half2* hp = (const __half2*)&h16[cur][kh * 128];
    float sr = 0.f, sz = 0.f, sn = 0.f;
#pragma unroll
    for (int i0 = 0; i0 < 64; i0 += 8) {
      __half2 ar = __float2half2_rn(0.f);
      __half2 az = __float2half2_rn(0.f);
      __half2 an = __float2half2_rn(0.f);
#pragma unroll
      for (int i = 0; i < 8; ++i) {
        const __half2 hv = hp[i0 + i];
        ar = __hfma2(wr[i0 + i], hv, ar);
        az = __hfma2(wz[i0 + i], hv, az);
        an = __hfma2(wn[i0 + i], hv, an);
      }
      sr += __low2float(ar) + __high2float(ar);
      sz += __low2float(az) + __high2float(az);
      sn += __low2float(an) + __high2float(an);
    }
    sr += __shfl_xor(sr, 1);
    sz += __shfl_xor(sz, 1);
    sn += __shfl_xor(sn, 1);
    if (kh == 0) {
      const float* xt = xrow + (long)t * 768;
      const float xr = xt[j], xz = xt[256 + j], xn = xt[512 + j];
      const float rr = 1.f / (1.f + __expf(-(xr + sr + br)));
      const float zg = 1.f / (1.f + __expf(-(xz + sz + bz)));
      const float narg = xn + rr * (sn + bn);
      const float e = __expf(-2.f * fabsf(narg));
      const float nv = copysignf((1.f - e) / (1.f + e), narg);
      const float hnew = (1.f - zg) * nv + zg * h32[cur][j];
      h32[cur ^ 1][j] = hnew;
      h16[cur ^ 1][j] = __float2half(hnew);
      if (yrow) yrow[(long)t * 256 + j] = hnew;
    }
    __syncthreads();
    cur ^= 1;
  }
  if (hT && kh == 0) hT[(long)c * 256 + j] = h32[cur][j];
}

// ---------------- dot-product attention: out = softmax(q kv^T / 16) kv -----
// one block per (b,q); q,kv have feature dim 256; kv length L <= 64.
__global__ __launch_bounds__(256) void k_attn(
    const float* __restrict__ q, const float* __restrict__ kv,
    float* __restrict__ out, int Q, int L)
{
  const int bq = blockIdx.x;
  const int b = bq / Q;
  const int tid = threadIdx.x;
  __shared__ float qv[256];
  __shared__ float sc[64];
  qv[tid] = q[(long)bq * 256 + tid];
  __syncthreads();
  if (tid < L) {
    const float* kr = kv + ((long)b * L + tid) * 256;
    float s = 0.f;
    for (int d = 0; d < 256; ++d) s += qv[d] * kr[d];
    sc[tid] = s * 0.0625f;
  }
  __syncthreads();
  float m = -1e30f;
  for (int k = 0; k < L; ++k) m = fmaxf(m, sc[k]);
  float den = 0.f;
  for (int k = 0; k < L; ++k) den += __expf(sc[k] - m);
  const float* kb = kv + (long)b * L * 256;
  float acc = 0.f;
  for (int k = 0; k < L; ++k) acc += __expf(sc[k] - m) * kb[(long)k * 256 + tid];
  out[(long)bq * 256 + tid] = acc / den;
}

// ---------------- hierarchy attention weights ------------------------------
// ahier[b][q][s] = softmax_s( dec[b,q,:] . g4out[s][b,:] / 16 ), one wave/block
__global__ __launch_bounds__(64) void k_hier(
    const float* __restrict__ dec, const float* __restrict__ g4out,
    float* __restrict__ ahier, int Q)
{
  const int bq = blockIdx.x;
  const int b = bq / Q;
  const int l = threadIdx.x;
  float s[4] = {0.f, 0.f, 0.f, 0.f};
#pragma unroll
  for (int i = 0; i < 4; ++i) {
    const int d = l * 4 + i;
    const float qd = dec[(long)bq * 256 + d];
#pragma unroll
    for (int sg = 0; sg < 4; ++sg)
      s[sg] += qd * g4out[((long)sg * 32 + b) * 256 + d];
  }
#pragma unroll
  for (int off = 32; off >= 1; off >>= 1)
#pragma unroll
    for (int sg = 0; sg < 4; ++sg) s[sg] += __shfl_xor(s[sg], off);
  if (l == 0) {
    float m = -1e30f;
#pragma unroll
    for (int sg = 0; sg < 4; ++sg) m = fmaxf(m, s[sg] * 0.0625f);
    float e[4], den = 0.f;
#pragma unroll
    for (int sg = 0; sg < 4; ++sg) { e[sg] = __expf(s[sg] * 0.0625f - m); den += e[sg]; }
#pragma unroll
    for (int sg = 0; sg < 4; ++sg) ahier[(long)bq * 4 + sg] = e[sg] / den;
  }
}

// ---------------- per-subgraph node attention + hierarchical combine -------
// one block per (s,b); loops q. actx1 += ahier[b,q,s] * softmax_k(dec.outs/16) outs
__global__ __launch_bounds__(256) void k_sc(
    const float* __restrict__ dec,   // [32][30][256]
    const float* __restrict__ outs,  // [4][32][300][256]
    const float* __restrict__ ahier, // [32][30][4]
    float* __restrict__ actx1)       // [32][30][256] (atomicAdd, pre-zeroed)
{
  const int sb = blockIdx.x;
  const int s = sb / 32, b = sb - s * 32;
  const int tid = threadIdx.x;
  const float* ob = outs + ((long)s * 32 + b) * 300 * 256;
  __shared__ float qv[256];
  __shared__ float p[304];
  for (int q = 0; q < 30; ++q) {
    qv[tid] = dec[((long)b * 30 + q) * 256 + tid];
    __syncthreads();
    for (int k = tid; k < 300; k += 256) {
      const float* orow = ob + (long)k * 256;
      float sc2 = 0.f;
      for (int d = 0; d < 256; ++d) sc2 += qv[d] * orow[d];
      p[k] = sc2 * 0.0625f;
    }
    __syncthreads();
    float m = -1e30f;
    for (int k = 0; k < 300; ++k) m = fmaxf(m, p[k]);
    float den = 0.f;
    for (int k = 0; k < 300; ++k) den += __expf(p[k] - m);
    __syncthreads();
    const float wsc = ahier[((long)b * 30 + q) * 4 + s] / den;
    for (int k = tid; k < 300; k += 256) p[k] = __expf(p[k] - m) * wsc;
    __syncthreads();
    float acc = 0.f;
    for (int k = 0; k < 300; ++k) acc += p[k] * ob[(long)k * 256 + tid];
    atomicAdd(&actx1[((long)b * 30 + q) * 256 + tid], acc);
    __syncthreads();
  }
}

// ---------------- concat [tctx | dec | actx] -> [960][768] ------------------
__global__ __launch_bounds__(256) void k_concat(
    const float* __restrict__ a, const float* __restrict__ b,
    const float* __restrict__ c, float* __restrict__ out, int rows)
{
  const int total = rows * 768;
  for (int i = blockIdx.x * 256 + threadIdx.x; i < total; i += gridDim.x * 256) {
    const int r = i / 768, col = i - r * 768;
    float v;
    if (col < 256) v = a[(long)r * 256 + col];
    else if (col < 512) v = b[(long)r * 256 + col - 256];
    else v = c[(long)r * 256 + col - 512];
    out[i] = v;
  }
}

// ---------------------------------------------------------------------------
extern "C" void kernel_launch(void* const* d_in, const int* in_sizes, int n_in,
                              void* d_out, int out_size, void* d_ws, size_t ws_size,
                              hipStream_t stream) {
  const int*   x0      = (const int*)d_in[0];
  const int*   x1      = (const int*)d_in[1];
  const int*   x2      = (const int*)d_in[2];
  const float* adj     = (const float*)d_in[3];
  const float* emb_ast = (const float*)d_in[4];
  const float* emb_com = (const float*)d_in[5];
  const float* g1_wih  = (const float*)d_in[6];
  const float* g1_whh  = (const float*)d_in[7];
  const float* g1_bih  = (const float*)d_in[8];
  const float* g1_bhh  = (const float*)d_in[9];
  const float* g2_wih  = (const float*)d_in[10];
  const float* g2_whh  = (const float*)d_in[11];
  const float* g2_bih  = (const float*)d_in[12];
  const float* g2_bhh  = (const float*)d_in[13];
  const float* g4_wih  = (const float*)d_in[14];
  const float* g4_whh  = (const float*)d_in[15];
  const float* g4_bih  = (const float*)d_in[16];
  const float* g4_bhh  = (const float*)d_in[17];
  const float* g58_wih = (const float*)d_in[18];
  const float* g58_whh = (const float*)d_in[19];
  const float* g58_bih = (const float*)d_in[20];
  const float* g58_bhh = (const float*)d_in[21];
  const float* gcn_w   = (const float*)d_in[22];
  const float* gcn_b   = (const float*)d_in[23];
  const float* dw      = (const float*)d_in[24];
  const float* db      = (const float*)d_in[25];
  const float* lw      = (const float*)d_in[26];
  const float* lb      = (const float*)d_in[27];
  float* out = (float*)d_out;
  float* ws  = (float*)d_ws;

  // workspace layout (float offsets)
  float* astwork = ws + 0L;         // [4][32][300][300]  11,520,000
  float* tmp     = ws + 11520000L;  // support / concat   11,520,000
  float* g58xg   = ws + 23040000L;  // [4][32][300][768]  29,491,200
  float* outsb   = ws + 52531200L;  // [4][32][300][256]   9,830,400
  float* xg1     = ws + 62361600L;  // [32][50][768]
  float* tenc    = ws + 63590400L;  // [32][50][256]
  float* tstate  = ws + 64000000L;  // [32][256]
  float* xg2     = ws + 64008192L;  // [32][30][768]
  float* dec     = ws + 64745472L;  // [32][30][256]
  float* tctx    = ws + 64991232L;  // [32][30][256]
  float* g4xg    = ws + 65236992L;  // [4][32][768]
  float* g4out   = ws + 65335296L;  // [4][32][256]
  float* ahier   = ws + 65368064L;  // [32][30][4]
  float* actx1   = ws + 65371904L;  // [32][30][256]
  float* actx    = ws + 65617664L;  // [32][30][256]
  float* dense   = ws + 65863424L;  // [32][30][256]

  const dim3 blk(256);

  // 1) gather astwork = emb_ast[x2] transposed to [s][b][n][d]
  k_gather_ast<<<dim3(4096), blk, 0, stream>>>(emb_ast, x2, astwork);

  // 2) GCN, 2 hops: support = astwork @ gcn_w ; astwork = relu(adj' @ support + b)
  for (int hop = 0; hop < 2; ++hop) {
    k_gemm<false, false, false, false><<<dim3(5, 5, 128), blk, 0, stream>>>(
        astwork, 300, 2880000, 90000,
        gcn_w, 300, 0, 0,
        tmp, 300, 2880000, 90000,
        nullptr, 0, nullptr, 300, 300, 300, 32, 1);
    k_gemm<false, true, false, false><<<dim3(5, 5, 128), blk, 0, stream>>>(
        adj, 300, 90000, 360000,          // adjp[s][b] = adj[b][s]
        tmp, 300, 2880000, 90000,
        astwork, 300, 2880000, 90000,
        gcn_b, 0, nullptr, 300, 300, 300, 32, 1);
  }

  // 3) token encoder GRU1
  k_gemm<true, false, true, false><<<dim3(12, 25, 1), blk, 0, stream>>>(
      emb_ast, 300, 0, 0, g1_wih, 300, 0, 0, xg1, 768, 0, 0,
      g1_bih, 0, x0, 1600, 768, 300, 1, 1);
  k_gru_seq<<<dim3(32), dim3(512), 0, stream>>>(
      xg1, nullptr, 1, g1_whh, 0, 1, g1_bhh, 0, tenc, tstate, 50);

  // 4) comment decoder GRU2
  k_gemm<true, false, true, false><<<dim3(12, 15, 1), blk, 0, stream>>>(
      emb_com, 300, 0, 0, g2_wih, 300, 0, 0, xg2, 768, 0, 0,
      g2_bih, 0, x1, 960, 768, 300, 1, 1);
  k_gru_seq<<<dim3(32), dim3(512), 0, stream>>>(
      xg2, tstate, 32, g2_whh, 0, 1, g2_bhh, 0, dec, nullptr, 30);

  // 5) tcontext = dot_attn(dec, tenc)
  k_attn<<<dim3(960), blk, 0, stream>>>(dec, tenc, tctx, 30, 50);

  // 6) gru4 over flattened node feats (K=90000, split-K=30, atomic)
  k_init_bias<<<dim3(384), blk, 0, stream>>>(g4xg, g4_bih, 128, 768);
  k_gemm<true, false, false, true><<<dim3(12, 2, 30), blk, 0, stream>>>(
      astwork, 90000, 0, 0, g4_wih, 90000, 0, 0, g4xg, 768, 0, 0,
      nullptr, 0, nullptr, 128, 768, 90000, 1, 30);
  k_gru_seq<<<dim3(4), dim3(512), 0, stream>>>(
      g4xg, nullptr, 1, g4_whh, 0, 1, g4_bhh, 0, g4out, nullptr, 32);

  // 7) hierarchy attention weights
  k_hier<<<dim3(960), dim3(64), 0, stream>>>(dec, g4out, ahier, 30);

  // 8) gru5..8 input gates (batched per-subgraph weights) + recurrence
  k_gemm<true, false, false, false><<<dim3(12, 150, 4), blk, 0, stream>>>(
      astwork, 300, 2880000, 0, g58_wih, 300, 230400, 0, g58xg, 768, 7372800, 0,
      g58_bih, 768, nullptr, 9600, 768, 300, 1, 1);
  k_gru_seq<<<dim3(128), dim3(512), 0, stream>>>(
      g58xg, tstate, 32, g58_whh, 196608, 32, g58_bhh, 768, outsb, nullptr, 300);

  // 9) node attention + hierarchical combine
  hipMemsetAsync(actx1, 0, 245760 * sizeof(float), stream);
  k_sc<<<dim3(128), blk, 0, stream>>>(dec, outsb, ahier, actx1);

  // 10) acontext = dot_attn(dec, actx1)
  k_attn<<<dim3(960), blk, 0, stream>>>(dec, actx1, actx, 30, 30);

  // 11) concat + dense (relu)
  k_concat<<<dim3(2880), blk, 0, stream>>>(tctx, dec, actx, tmp, 960);
  k_gemm<true, true, false, false><<<dim3(4, 15, 1), blk, 0, stream>>>(
      tmp, 768, 0, 0, dw, 768, 0, 0, dense, 256, 0, 0,
      db, 0, nullptr, 960, 256, 768, 1, 1);

  // 12) final linear: [32,7680] @ lin_w^T + lin_b (split-K=4, atomic)
  k_init_bias<<<dim3(1250), blk, 0, stream>>>(out, lb, 32, 10000);
  k_gemm<true, false, false, true><<<dim3(157, 1, 4), blk, 0, stream>>>(
      dense, 7680, 0, 0, lw, 7680, 0, 0, out, 10000, 0, 0,
      nullptr, 0, nullptr, 32, 10000, 7680, 1, 4);
}

// Round 2
// 3406.691 us; speedup vs baseline: 1.3231x; 1.3231x over previous
//
#include <hip/hip_runtime.h>
#include <hip/hip_fp16.h>
#include <hip/hip_bf16.h>

// ---------------------------------------------------------------------------
// HAConvGNN forward. fp32 compute; GRU recurrent weights cached in registers
// as f16 (hfma2 dots, f32 flush every 8 pairs).
// Round 2: k_sc (1135us, 25% of total) replaced by batched GEMM + wave
// softmax + batched GEMM; k_attn score phase parallelized.
// ---------------------------------------------------------------------------

// ---------------- generic fp32 tiled GEMM ----------------------------------
// C[M,N] = A(@rows, maybe gathered)[M,K] * B + bias, optional relu,
// batched via z = (s,b) decomposition, optional atomic split-K.
// BT: B stored [N,K] (C = A*B^T). !BT: B stored [K,N].
template <bool BT, bool RELU, bool GATHER, bool ATOMIC>
__global__ __launch_bounds__(256) void k_gemm(
    const float* __restrict__ A, long lda, long a_ss, long a_sb,
    const float* __restrict__ B, long ldb, long b_ss, long b_sb,
    float* __restrict__ C, long ldc, long c_ss, long c_sb,
    const float* __restrict__ bias, long bias_ss,
    const int* __restrict__ gidx,
    int M, int N, int K, int zb, int ksplit)
{
  __shared__ float As[16][68];
  __shared__ float Bs[16][68];
  const int tid = threadIdx.x;
  const int zi = blockIdx.z;
  const int bi = zi / ksplit;
  const int ks = zi - bi * ksplit;
  const int sIdx = bi / zb;
  const int bIdx = bi - sIdx * zb;
  const int row0 = blockIdx.y * 64;
  const int col0 = blockIdx.x * 64;
  const int Kc = (K + ksplit - 1) / ksplit;
  const int kbeg = ks * Kc;
  const int kend = min(K, kbeg + Kc);

  const float* Ab = A + (long)sIdx * a_ss + (long)bIdx * a_sb;
  const float* Bb = B + (long)sIdx * b_ss + (long)bIdx * b_sb;
  float* Cb = C + (long)sIdx * c_ss + (long)bIdx * c_sb;

  const int tx = tid & 15, ty = tid >> 4;
  float acc[4][4];
#pragma unroll
  for (int i = 0; i < 4; ++i)
#pragma unroll
    for (int j = 0; j < 4; ++j) acc[i][j] = 0.f;

  // A tile load mapping: 64 rows x 16 k, 4 elems/thread
  const int ar = tid >> 2;
  const int ac = (tid & 3) * 4;
  const int am = row0 + ar;
  const bool amok = am < M;
  const float* arow;
  if (GATHER) arow = A + (amok ? (long)gidx[am] * lda : 0);
  else        arow = Ab + (long)am * lda;

  for (int kt = kbeg; kt < kend; kt += 16) {
#pragma unroll
    for (int j = 0; j < 4; ++j) {
      const int kk = kt + ac + j;
      As[ac + j][ar] = (amok && kk < kend) ? arow[kk] : 0.f;
    }
    if (BT) {
      const int br = tid >> 2;            // n-local
      const int bc = (tid & 3) * 4;       // k-local
      const int nn = col0 + br;
      const bool bok = nn < N;
      const float* brow = Bb + (long)nn * ldb;
#pragma unroll
      for (int j = 0; j < 4; ++j) {
        const int kk = kt + bc + j;
        Bs[bc + j][br] = (bok && kk < kend) ? brow[kk] : 0.f;
      }
    } else {
      const int br = tid >> 4;            // k-local
      const int bc = (tid & 15) * 4;      // n-local
      const int kk = kt + br;
      const float* brow = Bb + (long)kk * ldb;
#pragma unroll
      for (int j = 0; j < 4; ++j) {
        const int nn = col0 + bc + j;
        Bs[br][bc + j] = (kk < kend && nn < N) ? brow[nn] : 0.f;
      }
    }
    __syncthreads();
#pragma unroll
    for (int kk = 0; kk < 16; ++kk) {
      const float4 av = *(const float4*)&As[kk][ty * 4];
      const float4 bv = *(const float4*)&Bs[kk][tx * 4];
      const float aa[4] = {av.x, av.y, av.z, av.w};
      const float bb[4] = {bv.x, bv.y, bv.z, bv.w};
#pragma unroll
      for (int i = 0; i < 4; ++i)
#pragma unroll
        for (int j = 0; j < 4; ++j)
          acc[i][j] = fmaf(aa[i], bb[j], acc[i][j]);
    }
    __syncthreads();
  }

  const float* biasp = bias ? bias + (long)sIdx * bias_ss : nullptr;
#pragma unroll
  for (int i = 0; i < 4; ++i) {
    const int m = row0 + ty * 4 + i;
    if (m >= M) continue;
    float* crow = Cb + (long)m * ldc;
#pragma unroll
    for (int j = 0; j < 4; ++j) {
      const int n = col0 + tx * 4 + j;
      if (n >= N) continue;
      if (ATOMIC) {
        atomicAdd(&crow[n], acc[i][j]);
      } else {
        float v = acc[i][j];
        if (biasp) v += biasp[n];
        if (RELU) v = fmaxf(v, 0.f);
        crow[n] = v;
      }
    }
  }
}

// ---------------- C[M,N] = bias[N] (init for atomic split-K) ---------------
__global__ __launch_bounds__(256) void k_init_bias(
    float* __restrict__ C, const float* __restrict__ bias, int M, int N)
{
  const int total = M * N;
  for (int i = blockIdx.x * 256 + threadIdx.x; i < total; i += gridDim.x * 256)
    C[i] = bias[i % N];
}

// ---------------- astwork[s][b][n][d] = emb_ast[x2[b][s][n]][d] ------------
__global__ __launch_bounds__(256) void k_gather_ast(
    const float* __restrict__ emb, const int* __restrict__ x2,
    float* __restrict__ outp)
{
  const int total = 4 * 32 * 300 * 300;
  for (int idx = blockIdx.x * 256 + threadIdx.x; idx < total; idx += gridDim.x * 256) {
    const int d = idx % 300;
    const int r = idx / 300;
    const int n = r % 300;
    const int r2 = r / 300;
    const int b = r2 % 32;
    const int s = r2 / 32;
    outp[idx] = emb[(long)x2[(b * 4 + s) * 300 + n] * 300 + d];
  }
}

// ---------------- GRU sequence: one block per independent chain ------------
// xg [C][T][768] precomputed (incl. bih). whh cached in regs as f16.
// Thread t: unit j = t>>1 owns K-half kh = t&1 (128 of 256).
__global__ __launch_bounds__(512) void k_gru_seq(
    const float* __restrict__ xg,
    const float* __restrict__ h0, int h0_mod,
    const float* __restrict__ whh, long w_stride, int cpw,
    const float* __restrict__ bhh, long b_stride,
    float* __restrict__ ys, float* __restrict__ hT, int T)
{
  const int c = blockIdx.x;
  const int tid = threadIdx.x;
  const int j = tid >> 1;
  const int kh = tid & 1;
  const int w = c / cpw;
  const float* W = whh + (long)w * w_stride;
  const float* Bh = bhh + (long)w * b_stride;

  __half2 wr[64], wz[64], wn[64];
  {
    const float* pr = W + (long)j * 256 + kh * 128;
    const float* pz = W + (long)(j + 256) * 256 + kh * 128;
    const float* pn = W + (long)(j + 512) * 256 + kh * 128;
#pragma unroll
    for (int i = 0; i < 64; ++i) {
      wr[i] = __floats2half2_rn(pr[2 * i], pr[2 * i + 1]);
      wz[i] = __floats2half2_rn(pz[2 * i], pz[2 * i + 1]);
      wn[i] = __floats2half2_rn(pn[2 * i], pn[2 * i + 1]);
    }
  }
  const float br = Bh[j], bz = Bh[256 + j], bn = Bh[512 + j];

  __shared__ float  h32[2][256];
  __shared__ __half h16[2][256];
  if (kh == 0) {
    const float hv = h0 ? h0[(long)(c % h0_mod) * 256 + j] : 0.f;
    h32[0][j] = hv;
    h16[0][j] = __float2half(hv);
  }
  __syncthreads();

  const float* xrow = xg + (long)c * T * 768;
  float* yrow = ys ? ys + (long)c * T * 256 : nullptr;
  int cur = 0;
  for (int t = 0; t < T; ++t) {
    const __half2* hp = (const __half2*)&h16[cur][kh * 128];
    float sr = 0.f, sz = 0.f, sn = 0.f;
#pragma unroll
    for (int i0 = 0; i0 < 64; i0 += 8) {
      __half2 ar = __float2half2_rn(0.f);
      __half2 az = __float2half2_rn(0.f);
      __half2 an = __float2half2_rn(0.f);
#pragma unroll
      for (int i = 0; i < 8; ++i) {
        const __half2 hv = hp[i0 + i];
        ar = __hfma2(wr[i0 + i], hv, ar);
        az = __hfma2(wz[i0 + i], hv, az);
        an = __hfma2(wn[i0 + i], hv, an);
      }
      sr += __low2float(ar) + __high2float(ar);
      sz += __low2float(az) + __high2float(az);
      sn += __low2float(an) + __high2float(an);
    }
    sr += __shfl_xor(sr, 1);
    sz += __shfl_xor(sz, 1);
    sn += __shfl_xor(sn, 1);
    if (kh == 0) {
      const float* xt = xrow + (long)t * 768;
      const float xr = xt[j], xz = xt[256 + j], xn = xt[512 + j];
      const float rr = 1.f / (1.f + __expf(-(xr + sr + br)));
      const float zg = 1.f / (1.f + __expf(-(xz + sz + bz)));
      const float narg = xn + rr * (sn + bn);
      const float e = __expf(-2.f * fabsf(narg));
      const float nv = copysignf((1.f - e) / (1.f + e), narg);
      const float hnew = (1.f - zg) * nv + zg * h32[cur][j];
      h32[cur ^ 1][j] = hnew;
      h16[cur ^ 1][j] = __float2half(hnew);
      if (yrow) yrow[(long)t * 256 + j] = hnew;
    }
    __syncthreads();
    cur ^= 1;
  }
  if (hT && kh == 0) hT[(long)c * 256 + j] = h32[cur][j];
}

// ---------------- dot-product attention: out = softmax(q kv^T / 16) kv -----
// one block per (b,q); q,kv have feature dim 256; kv length L <= 64.
// score phase: 8 lanes per key row, shfl-reduced.
__global__ __launch_bounds__(256) void k_attn(
    const float* __restrict__ q, const float* __restrict__ kv,
    float* __restrict__ out, int Q, int L)
{
  const int bq = blockIdx.x;
  const int b = bq / Q;
  const int tid = threadIdx.x;
  const int g = tid >> 3, l = tid & 7;
  __shared__ float qv[256];
  __shared__ float sc[64];
  qv[tid] = q[(long)bq * 256 + tid];
  __syncthreads();
  for (int k0 = 0; k0 < L; k0 += 32) {
    const int k = k0 + g;
    float s = 0.f;
    if (k < L) {
      const float* kr = kv + ((long)b * L + k) * 256;
      for (int d = l; d < 256; d += 8) s += qv[d] * kr[d];
    }
    s += __shfl_xor(s, 1);
    s += __shfl_xor(s, 2);
    s += __shfl_xor(s, 4);
    if (k < L && l == 0) sc[k] = s * 0.0625f;
  }
  __syncthreads();
  float m = -1e30f;
  for (int k = 0; k < L; ++k) m = fmaxf(m, sc[k]);
  float den = 0.f;
  for (int k = 0; k < L; ++k) den += __expf(sc[k] - m);
  __syncthreads();
  if (tid < L) sc[tid] = __expf(sc[tid] - m);
  __syncthreads();
  const float* kb = kv + (long)b * L * 256;
  float acc = 0.f;
  for (int k = 0; k < L; ++k) acc += sc[k] * kb[(long)k * 256 + tid];
  out[(long)bq * 256 + tid] = acc / den;
}

// ---------------- hierarchy attention weights ------------------------------
// ahier[b][q][s] = softmax_s( dec[b,q,:] . g4out[s][b,:] / 16 ), one wave/block
__global__ __launch_bounds__(64) void k_hier(
    const float* __restrict__ dec, const float* __restrict__ g4out,
    float* __restrict__ ahier, int Q)
{
  const int bq = blockIdx.x;
  const int b = bq / Q;
  const int l = threadIdx.x;
  float s[4] = {0.f, 0.f, 0.f, 0.f};
#pragma unroll
  for (int i = 0; i < 4; ++i) {
    const int d = l * 4 + i;
    const float qd = dec[(long)bq * 256 + d];
#pragma unroll
    for (int sg = 0; sg < 4; ++sg)
      s[sg] += qd * g4out[((long)sg * 32 + b) * 256 + d];
  }
#pragma unroll
  for (int off = 32; off >= 1; off >>= 1)
#pragma unroll
    for (int sg = 0; sg < 4; ++sg) s[sg] += __shfl_xor(s[sg], off);
  if (l == 0) {
    float m = -1e30f;
#pragma unroll
    for (int sg = 0; sg < 4; ++sg) m = fmaxf(m, s[sg] * 0.0625f);
    float e[4], den = 0.f;
#pragma unroll
    for (int sg = 0; sg < 4; ++sg) { e[sg] = __expf(s[sg] * 0.0625f - m); den += e[sg]; }
#pragma unroll
    for (int sg = 0; sg < 4; ++sg) ahier[(long)bq * 4 + sg] = e[sg] / den;
  }
}

// ---------------- row softmax * hierarchy weight over sc[s][b][q][300] -----
// one wave per row; in-place. p = softmax(row*1/16) * ahier[b,q,s]
__global__ __launch_bounds__(64) void k_smax(
    float* __restrict__ sc, const float* __restrict__ ahier)
{
  const int id = blockIdx.x;          // s*960 + (b*30+q)
  const int s = id / 960;
  const int bq = id - s * 960;
  float* row = sc + (long)id * 300;
  const int l = threadIdx.x;
  float v[5];
  float m = -1e30f;
#pragma unroll
  for (int i = 0; i < 5; ++i) {
    const int k = l + i * 64;
    v[i] = (k < 300) ? row[k] * 0.0625f : -1e30f;
    m = fmaxf(m, v[i]);
  }
#pragma unroll
  for (int off = 32; off >= 1; off >>= 1) m = fmaxf(m, __shfl_xor(m, off));
  float den = 0.f;
#pragma unroll
  for (int i = 0; i < 5; ++i) { v[i] = __expf(v[i] - m); den += v[i]; }
#pragma unroll
  for (int off = 32; off >= 1; off >>= 1) den += __shfl_xor(den, off);
  const float w = ahier[(long)bq * 4 + s] / den;
#pragma unroll
  for (int i = 0; i < 5; ++i) {
    const int k = l + i * 64;
    if (k < 300) row[k] = v[i] * w;
  }
}

// ---------------- concat [tctx | dec | actx] -> [960][768] ------------------
__global__ __launch_bounds__(256) void k_concat(
    const float* __restrict__ a, const float* __restrict__ b,
    const float* __restrict__ c, float* __restrict__ out, int rows)
{
  const int total = rows * 768;
  for (int i = blockIdx.x * 256 + threadIdx.x; i < total; i += gridDim.x * 256) {
    const int r = i / 768, col = i - r * 768;
    float v;
    if (col < 256) v = a[(long)r * 256 + col];
    else if (col < 512) v = b[(long)r * 256 + col - 256];
    else v = c[(long)r * 256 + col - 512];
    out[i] = v;
  }
}

// ---------------------------------------------------------------------------
extern "C" void kernel_launch(void* const* d_in, const int* in_sizes, int n_in,
                              void* d_out, int out_size, void* d_ws, size_t ws_size,
                              hipStream_t stream) {
  const int*   x0      = (const int*)d_in[0];
  const int*   x1      = (const int*)d_in[1];
  const int*   x2      = (const int*)d_in[2];
  const float* adj     = (const float*)d_in[3];
  const float* emb_ast = (const float*)d_in[4];
  const float* emb_com = (const float*)d_in[5];
  const float* g1_wih  = (const float*)d_in[6];
  const float* g1_whh  = (const float*)d_in[7];
  const float* g1_bih  = (const float*)d_in[8];
  const float* g1_bhh  = (const float*)d_in[9];
  const float* g2_wih  = (const float*)d_in[10];
  const float* g2_whh  = (const float*)d_in[11];
  const float* g2_bih  = (const float*)d_in[12];
  const float* g2_bhh  = (const float*)d_in[13];
  const float* g4_wih  = (const float*)d_in[14];
  const float* g4_whh  = (const float*)d_in[15];
  const float* g4_bih  = (const float*)d_in[16];
  const float* g4_bhh  = (const float*)d_in[17];
  const float* g58_wih = (const float*)d_in[18];
  const float* g58_whh = (const float*)d_in[19];
  const float* g58_bih = (const float*)d_in[20];
  const float* g58_bhh = (const float*)d_in[21];
  const float* gcn_w   = (const float*)d_in[22];
  const float* gcn_b   = (const float*)d_in[23];
  const float* dw      = (const float*)d_in[24];
  const float* db      = (const float*)d_in[25];
  const float* lw      = (const float*)d_in[26];
  const float* lb      = (const float*)d_in[27];
  float* out = (float*)d_out;
  float* ws  = (float*)d_ws;

  // workspace layout (float offsets)
  float* astwork = ws + 0L;         // [4][32][300][300]  11,520,000
  float* tmp     = ws + 11520000L;  // support / concat   11,520,000
  float* scbuf   = ws + 13520000L;  // [4][32][30][300]    1,152,000 (inside tmp, disjoint from concat use)
  float* g58xg   = ws + 23040000L;  // [4][32][300][768]  29,491,200
  float* outsb   = ws + 52531200L;  // [4][32][300][256]   9,830,400
  float* xg1     = ws + 62361600L;  // [32][50][768]
  float* tenc    = ws + 63590400L;  // [32][50][256]
  float* tstate  = ws + 64000000L;  // [32][256]
  float* xg2     = ws + 64008192L;  // [32][30][768]
  float* dec     = ws + 64745472L;  // [32][30][256]
  float* tctx    = ws + 64991232L;  // [32][30][256]
  float* g4xg    = ws + 65236992L;  // [4][32][768]
  float* g4out   = ws + 65335296L;  // [4][32][256]
  float* ahier   = ws + 65368064L;  // [32][30][4]
  float* actx1   = ws + 65371904L;  // [32][30][256]
  float* actx    = ws + 65617664L;  // [32][30][256]
  float* dense   = ws + 65863424L;  // [32][30][256]

  const dim3 blk(256);

  // 1) gather astwork = emb_ast[x2] transposed to [s][b][n][d]
  k_gather_ast<<<dim3(4096), blk, 0, stream>>>(emb_ast, x2, astwork);

  // 2) GCN, 2 hops: support = astwork @ gcn_w ; astwork = relu(adj' @ support + b)
  for (int hop = 0; hop < 2; ++hop) {
    k_gemm<false, false, false, false><<<dim3(5, 5, 128), blk, 0, stream>>>(
        astwork, 300, 2880000, 90000,
        gcn_w, 300, 0, 0,
        tmp, 300, 2880000, 90000,
        nullptr, 0, nullptr, 300, 300, 300, 32, 1);
    k_gemm<false, true, false, false><<<dim3(5, 5, 128), blk, 0, stream>>>(
        adj, 300, 90000, 360000,          // adjp[s][b] = adj[b][s]
        tmp, 300, 2880000, 90000,
        astwork, 300, 2880000, 90000,
        gcn_b, 0, nullptr, 300, 300, 300, 32, 1);
  }

  // 3) token encoder GRU1
  k_gemm<true, false, true, false><<<dim3(12, 25, 1), blk, 0, stream>>>(
      emb_ast, 300, 0, 0, g1_wih, 300, 0, 0, xg1, 768, 0, 0,
      g1_bih, 0, x0, 1600, 768, 300, 1, 1);
  k_gru_seq<<<dim3(32), dim3(512), 0, stream>>>(
      xg1, nullptr, 1, g1_whh, 0, 1, g1_bhh, 0, tenc, tstate, 50);

  // 4) comment decoder GRU2
  k_gemm<true, false, true, false><<<dim3(12, 15, 1), blk, 0, stream>>>(
      emb_com, 300, 0, 0, g2_wih, 300, 0, 0, xg2, 768, 0, 0,
      g2_bih, 0, x1, 960, 768, 300, 1, 1);
  k_gru_seq<<<dim3(32), dim3(512), 0, stream>>>(
      xg2, tstate, 32, g2_whh, 0, 1, g2_bhh, 0, dec, nullptr, 30);

  // 5) tcontext = dot_attn(dec, tenc)
  k_attn<<<dim3(960), blk, 0, stream>>>(dec, tenc, tctx, 30, 50);

  // 6) gru4 over flattened node feats (K=90000, split-K=30, atomic)
  k_init_bias<<<dim3(384), blk, 0, stream>>>(g4xg, g4_bih, 128, 768);
  k_gemm<true, false, false, true><<<dim3(12, 2, 30), blk, 0, stream>>>(
      astwork, 90000, 0, 0, g4_wih, 90000, 0, 0, g4xg, 768, 0, 0,
      nullptr, 0, nullptr, 128, 768, 90000, 1, 30);
  k_gru_seq<<<dim3(4), dim3(512), 0, stream>>>(
      g4xg, nullptr, 1, g4_whh, 0, 1, g4_bhh, 0, g4out, nullptr, 32);

  // 7) hierarchy attention weights
  k_hier<<<dim3(960), dim3(64), 0, stream>>>(dec, g4out, ahier, 30);

  // 8) gru5..8 input gates (batched per-subgraph weights) + recurrence
  k_gemm<true, false, false, false><<<dim3(12, 150, 4), blk, 0, stream>>>(
      astwork, 300, 2880000, 0, g58_wih, 300, 230400, 0, g58xg, 768, 7372800, 0,
      g58_bih, 768, nullptr, 9600, 768, 300, 1, 1);
  k_gru_seq<<<dim3(128), dim3(512), 0, stream>>>(
      g58xg, tstate, 32, g58_whh, 196608, 32, g58_bhh, 768, outsb, nullptr, 300);

  // 9) node attention + hierarchical combine (GEMM-ified k_sc)
  //    scores: sc[s,b][q,k] = dec[b] @ outs[s,b]^T   (scale applied in k_smax)
  k_gemm<true, false, false, false><<<dim3(5, 1, 128), blk, 0, stream>>>(
      dec, 256, 0, 7680, outsb, 256, 2457600, 76800, scbuf, 300, 288000, 9000,
      nullptr, 0, nullptr, 30, 300, 256, 32, 1);
  k_smax<<<dim3(3840), dim3(64), 0, stream>>>(scbuf, ahier);
  hipMemsetAsync(actx1, 0, 245760 * sizeof(float), stream);
  //    PV: actx1[b][q][d] += P[s,b] @ outs[s,b]  (atomic over s)
  k_gemm<false, false, false, true><<<dim3(4, 1, 128), blk, 0, stream>>>(
      scbuf, 300, 288000, 9000, outsb, 256, 2457600, 76800, actx1, 256, 0, 7680,
      nullptr, 0, nullptr, 30, 256, 300, 32, 1);

  // 10) acontext = dot_attn(dec, actx1)
  k_attn<<<dim3(960), blk, 0, stream>>>(dec, actx1, actx, 30, 30);

  // 11) concat + dense (relu)
  k_concat<<<dim3(2880), blk, 0, stream>>>(tctx, dec, actx, tmp, 960);
  k_gemm<true, true, false, false><<<dim3(4, 15, 1), blk, 0, stream>>>(
      tmp, 768, 0, 0, dw, 768, 0, 0, dense, 256, 0, 0,
      db, 0, nullptr, 960, 256, 768, 1, 1);

  // 12) final linear: [32,7680] @ lin_w^T + lin_b (split-K=4, atomic)
  k_init_bias<<<dim3(1250), blk, 0, stream>>>(out, lb, 32, 10000);
  k_gemm<true, false, false, true><<<dim3(157, 1, 4), blk, 0, stream>>>(
      dense, 7680, 0, 0, lw, 7680, 0, 0, out, 10000, 0, 0,
      nullptr, 0, nullptr, 32, 10000, 7680, 1, 4);
}

// Round 3
// 1819.385 us; speedup vs baseline: 2.4774x; 1.8724x over previous
//
#include <hip/hip_runtime.h>
#include <hip/hip_fp16.h>
#include <hip/hip_bf16.h>

// ---------------------------------------------------------------------------
// HAConvGNN forward. Round 3: bf16 MFMA GEMMs for GCN / gru4 / g58 / final
// linear (fp32 operands converted to bf16 during LDS staging); astwork kept
// bf16 end-to-end; gru xg prefetch. fp32 path kept for small GEMMs.
// ---------------------------------------------------------------------------

typedef __attribute__((ext_vector_type(8))) short  bf16x8;
typedef __attribute__((ext_vector_type(4))) float  f32x4;

__device__ inline unsigned short f2bs(float f) {
  __hip_bfloat16 h = __float2bfloat16(f);
  unsigned short u; __builtin_memcpy(&u, &h, 2); return u;
}

// ---------------- bf16 MFMA GEMM -------------------------------------------
// C[M,N] = A[M,K] * B^T (B stored [N][K]) with batching z=(batch, ksplit).
// ABF/BBF: operand is bf16 in global (else fp32, converted during staging).
// OUTM: 0 = fp32 (+bias/relu), 1 = bf16 (+bias/relu), 2 = fp32 atomicAdd,
//       3 = transposed bf16 (writes C^T[N][M], ldc = stride of C^T rows).
template <bool ABF, bool BBF, int OUTM, bool RELU>
__global__ __launch_bounds__(256) void k_mfma(
    const void* __restrict__ Av, long lda, long a_ss, long a_sb,
    const void* __restrict__ Bv, long ldb, long b_ss, long b_sb,
    void* __restrict__ Cv, long ldc, long c_ss, long c_sb,
    const float* __restrict__ bias, long bias_ss,
    int M, int N, int K, int zb, int ksplit)
{
  __shared__ unsigned short As[128][40];  // 32 k + 8 pad
  __shared__ unsigned short Bs[128][40];
  const int tid = threadIdx.x;
  const int zi = blockIdx.z;
  const int bi = zi / ksplit;
  const int ks = zi - bi * ksplit;
  const int sIdx = bi / zb;
  const int bIdx = bi - sIdx * zb;
  const int row0 = blockIdx.y * 128;
  const int col0 = blockIdx.x * 128;
  const int Kc = ((K + ksplit * 32 - 1) / (ksplit * 32)) * 32;
  const int kbeg = ks * Kc;
  const int kend = min(K, kbeg + Kc);
  if (kbeg >= kend) return;

  const char* Ab = (const char*)Av + ((long)sIdx * a_ss + (long)bIdx * a_sb) * (ABF ? 2 : 4);
  const char* Bb = (const char*)Bv + ((long)sIdx * b_ss + (long)bIdx * b_sb) * (BBF ? 2 : 4);
  char* Cb = (char*)Cv + ((long)sIdx * c_ss + (long)bIdx * c_sb) * ((OUTM == 1 || OUTM == 3) ? 2 : 4);

  const int w = tid >> 6, l = tid & 63;
  const int wr = w >> 1, wc = w & 1;
  const int lr = l & 15, lg = l >> 4;

  f32x4 acc[4][4];
#pragma unroll
  for (int m = 0; m < 4; ++m)
#pragma unroll
    for (int n = 0; n < 4; ++n) acc[m][n] = f32x4{0.f, 0.f, 0.f, 0.f};

  const int sr = tid >> 1;          // staged row 0..127
  const int sk = (tid & 1) * 16;    // staged k base

  for (int kt = kbeg; kt < kend; kt += 32) {
    // ---- stage A tile [128 rows][32 k]
    {
      const int gr = row0 + sr;
      if (ABF) {
        const unsigned short* src = (const unsigned short*)(Ab + ((long)gr * lda + kt + sk) * 2);
        if (gr < M && kt + sk + 16 <= kend) {
          const uint2* p = (const uint2*)src;
          *(uint2*)&As[sr][sk + 0]  = p[0];
          *(uint2*)&As[sr][sk + 4]  = p[1];
          *(uint2*)&As[sr][sk + 8]  = p[2];
          *(uint2*)&As[sr][sk + 12] = p[3];
        } else {
#pragma unroll
          for (int i = 0; i < 16; ++i) {
            const int kk = kt + sk + i;
            As[sr][sk + i] = (gr < M && kk < kend) ? src[i] : (unsigned short)0;
          }
        }
      } else {
        const float* src = (const float*)(Ab + ((long)gr * lda + kt + sk) * 4);
        if (gr < M && kt + sk + 16 <= kend) {
#pragma unroll
          for (int q = 0; q < 4; ++q) {
            const float4 v = ((const float4*)src)[q];
            *(unsigned*)&As[sr][sk + q * 4 + 0] = (unsigned)f2bs(v.x) | ((unsigned)f2bs(v.y) << 16);
            *(unsigned*)&As[sr][sk + q * 4 + 2] = (unsigned)f2bs(v.z) | ((unsigned)f2bs(v.w) << 16);
          }
        } else {
#pragma unroll
          for (int i = 0; i < 16; ++i) {
            const int kk = kt + sk + i;
            As[sr][sk + i] = (gr < M && kk < kend) ? f2bs(src[i]) : (unsigned short)0;
          }
        }
      }
    }
    // ---- stage B tile [128 cols][32 k] (B stored [N][K])
    {
      const int gc = col0 + sr;
      if (BBF) {
        const unsigned short* src = (const unsigned short*)(Bb + ((long)gc * ldb + kt + sk) * 2);
        if (gc < N && kt + sk + 16 <= kend) {
          const uint2* p = (const uint2*)src;
          *(uint2*)&Bs[sr][sk + 0]  = p[0];
          *(uint2*)&Bs[sr][sk + 4]  = p[1];
          *(uint2*)&Bs[sr][sk + 8]  = p[2];
          *(uint2*)&Bs[sr][sk + 12] = p[3];
        } else {
#pragma unroll
          for (int i = 0; i < 16; ++i) {
            const int kk = kt + sk + i;
            Bs[sr][sk + i] = (gc < N && kk < kend) ? src[i] : (unsigned short)0;
          }
        }
      } else {
        const float* src = (const float*)(Bb + ((long)gc * ldb + kt + sk) * 4);
        if (gc < N && kt + sk + 16 <= kend) {
#pragma unroll
          for (int q = 0; q < 4; ++q) {
            const float4 v = ((const float4*)src)[q];
            *(unsigned*)&Bs[sr][sk + q * 4 + 0] = (unsigned)f2bs(v.x) | ((unsigned)f2bs(v.y) << 16);
            *(unsigned*)&Bs[sr][sk + q * 4 + 2] = (unsigned)f2bs(v.z) | ((unsigned)f2bs(v.w) << 16);
          }
        } else {
#pragma unroll
          for (int i = 0; i < 16; ++i) {
            const int kk = kt + sk + i;
            Bs[sr][sk + i] = (gc < N && kk < kend) ? f2bs(src[i]) : (unsigned short)0;
          }
        }
      }
    }
    __syncthreads();
    // ---- compute: wave (wr,wc) owns 64x64; 4x4 frags of 16x16, K=32
    bf16x8 af[4], bf[4];
#pragma unroll
    for (int m = 0; m < 4; ++m)
      af[m] = *(const bf16x8*)&As[wr * 64 + m * 16 + lr][lg * 8];
#pragma unroll
    for (int n = 0; n < 4; ++n)
      bf[n] = *(const bf16x8*)&Bs[wc * 64 + n * 16 + lr][lg * 8];
#pragma unroll
    for (int m = 0; m < 4; ++m)
#pragma unroll
      for (int n = 0; n < 4; ++n)
        acc[m][n] = __builtin_amdgcn_mfma_f32_16x16x32_bf16(af[m], bf[n], acc[m][n], 0, 0, 0);
    __syncthreads();
  }

  // ---- epilogue
  const float* bp = bias ? bias + (long)sIdx * bias_ss : nullptr;
#pragma unroll
  for (int m = 0; m < 4; ++m) {
#pragma unroll
    for (int n = 0; n < 4; ++n) {
      const int col = col0 + wc * 64 + n * 16 + lr;
      const int rb  = row0 + wr * 64 + m * 16 + lg * 4;
      const f32x4 v = acc[m][n];
      if (col >= N) continue;
      if (OUTM == 3) {
        unsigned short* ct = (unsigned short*)Cb + (long)col * ldc + rb;
        if (rb + 4 <= M) {
          ushort4 pk;
          pk.x = f2bs(v[0]); pk.y = f2bs(v[1]); pk.z = f2bs(v[2]); pk.w = f2bs(v[3]);
          *(ushort4*)ct = pk;
        } else {
#pragma unroll
          for (int r = 0; r < 4; ++r) if (rb + r < M) ct[r] = f2bs(v[r]);
        }
      } else {
        const float bv = bp ? bp[col] : 0.f;
#pragma unroll
        for (int r = 0; r < 4; ++r) {
          const int row = rb + r;
          if (row >= M) continue;
          float x = v[r] + bv;
          if (RELU) x = fmaxf(x, 0.f);
          if (OUTM == 0) ((float*)Cb)[(long)row * ldc + col] = x;
          else if (OUTM == 1) ((unsigned short*)Cb)[(long)row * ldc + col] = f2bs(x);
          else atomicAdd((float*)Cb + (long)row * ldc + col, x);
        }
      }
    }
  }
}

// ---------------- generic fp32 tiled GEMM (small shapes) --------------------
template <bool BT, bool RELU, bool GATHER, bool ATOMIC>
__global__ __launch_bounds__(256) void k_gemm(
    const float* __restrict__ A, long lda, long a_ss, long a_sb,
    const float* __restrict__ B, long ldb, long b_ss, long b_sb,
    float* __restrict__ C, long ldc, long c_ss, long c_sb,
    const float* __restrict__ bias, long bias_ss,
    const int* __restrict__ gidx,
    int M, int N, int K, int zb, int ksplit)
{
  __shared__ float As[16][68];
  __shared__ float Bs[16][68];
  const int tid = threadIdx.x;
  const int zi = blockIdx.z;
  const int bi = zi / ksplit;
  const int ks = zi - bi * ksplit;
  const int sIdx = bi / zb;
  const int bIdx = bi - sIdx * zb;
  const int row0 = blockIdx.y * 64;
  const int col0 = blockIdx.x * 64;
  const int Kc = (K + ksplit - 1) / ksplit;
  const int kbeg = ks * Kc;
  const int kend = min(K, kbeg + Kc);

  const float* Ab = A + (long)sIdx * a_ss + (long)bIdx * a_sb;
  const float* Bb = B + (long)sIdx * b_ss + (long)bIdx * b_sb;
  float* Cb = C + (long)sIdx * c_ss + (long)bIdx * c_sb;

  const int tx = tid & 15, ty = tid >> 4;
  float acc[4][4];
#pragma unroll
  for (int i = 0; i < 4; ++i)
#pragma unroll
    for (int j = 0; j < 4; ++j) acc[i][j] = 0.f;

  const int ar = tid >> 2;
  const int ac = (tid & 3) * 4;
  const int am = row0 + ar;
  const bool amok = am < M;
  const float* arow;
  if (GATHER) arow = A + (amok ? (long)gidx[am] * lda : 0);
  else        arow = Ab + (long)am * lda;

  for (int kt = kbeg; kt < kend; kt += 16) {
#pragma unroll
    for (int j = 0; j < 4; ++j) {
      const int kk = kt + ac + j;
      As[ac + j][ar] = (amok && kk < kend) ? arow[kk] : 0.f;
    }
    if (BT) {
      const int br = tid >> 2;
      const int bc = (tid & 3) * 4;
      const int nn = col0 + br;
      const bool bok = nn < N;
      const float* brow = Bb + (long)nn * ldb;
#pragma unroll
      for (int j = 0; j < 4; ++j) {
        const int kk = kt + bc + j;
        Bs[bc + j][br] = (bok && kk < kend) ? brow[kk] : 0.f;
      }
    } else {
      const int br = tid >> 4;
      const int bc = (tid & 15) * 4;
      const int kk = kt + br;
      const float* brow = Bb + (long)kk * ldb;
#pragma unroll
      for (int j = 0; j < 4; ++j) {
        const int nn = col0 + bc + j;
        Bs[br][bc + j] = (kk < kend && nn < N) ? brow[nn] : 0.f;
      }
    }
    __syncthreads();
#pragma unroll
    for (int kk = 0; kk < 16; ++kk) {
      const float4 av = *(const float4*)&As[kk][ty * 4];
      const float4 bv = *(const float4*)&Bs[kk][tx * 4];
      const float aa[4] = {av.x, av.y, av.z, av.w};
      const float bb[4] = {bv.x, bv.y, bv.z, bv.w};
#pragma unroll
      for (int i = 0; i < 4; ++i)
#pragma unroll
        for (int j = 0; j < 4; ++j)
          acc[i][j] = fmaf(aa[i], bb[j], acc[i][j]);
    }
    __syncthreads();
  }

  const float* biasp = bias ? bias + (long)sIdx * bias_ss : nullptr;
#pragma unroll
  for (int i = 0; i < 4; ++i) {
    const int m = row0 + ty * 4 + i;
    if (m >= M) continue;
    float* crow = Cb + (long)m * ldc;
#pragma unroll
    for (int j = 0; j < 4; ++j) {
      const int n = col0 + tx * 4 + j;
      if (n >= N) continue;
      if (ATOMIC) {
        atomicAdd(&crow[n], acc[i][j]);
      } else {
        float v = acc[i][j];
        if (biasp) v += biasp[n];
        if (RELU) v = fmaxf(v, 0.f);
        crow[n] = v;
      }
    }
  }
}

// ---------------- C[M,N] = bias[N] ------------------------------------------
__global__ __launch_bounds__(256) void k_init_bias(
    float* __restrict__ C, const float* __restrict__ bias, int M, int N)
{
  const int total = M * N;
  for (int i = blockIdx.x * 256 + threadIdx.x; i < total; i += gridDim.x * 256)
    C[i] = bias[i % N];
}

// ---------------- astwork_bf[s][b][n][d] = bf16(emb_ast[x2[b][s][n]][d]) ----
__global__ __launch_bounds__(256) void k_gather_ast(
    const float* __restrict__ emb, const int* __restrict__ x2,
    unsigned short* __restrict__ outp)
{
  const int total = 4 * 32 * 300 * 300;
  for (int idx = blockIdx.x * 256 + threadIdx.x; idx < total; idx += gridDim.x * 256) {
    const int d = idx % 300;
    const int r = idx / 300;
    const int n = r % 300;
    const int r2 = r / 300;
    const int b = r2 % 32;
    const int s = r2 / 32;
    outp[idx] = f2bs(emb[(long)x2[(b * 4 + s) * 300 + n] * 300 + d]);
  }
}

// ---------------- oT[c][r] = bf16(w[r][c]) ----------------------------------
__global__ __launch_bounds__(256) void k_twb(
    const float* __restrict__ w, unsigned short* __restrict__ o, int R, int C)
{
  const int total = R * C;
  for (int i = blockIdx.x * 256 + threadIdx.x; i < total; i += gridDim.x * 256) {
    const int r = i / C, c = i - r * C;
    o[(long)c * R + r] = f2bs(w[i]);
  }
}

// ---------------- fp32 -> bf16 copy ----------------------------------------
__global__ __launch_bounds__(256) void k_f2b(
    const float* __restrict__ a, unsigned short* __restrict__ o, int n)
{
  for (int i = blockIdx.x * 256 + threadIdx.x; i < n; i += gridDim.x * 256)
    o[i] = f2bs(a[i]);
}

// ---------------- GRU sequence: one block per independent chain ------------
__global__ __launch_bounds__(512) void k_gru_seq(
    const float* __restrict__ xg,
    const float* __restrict__ h0, int h0_mod,
    const float* __restrict__ whh, long w_stride, int cpw,
    const float* __restrict__ bhh, long b_stride,
    float* __restrict__ ys, float* __restrict__ hT, int T)
{
  const int c = blockIdx.x;
  const int tid = threadIdx.x;
  const int j = tid >> 1;
  const int kh = tid & 1;
  const int w = c / cpw;
  const float* W = whh + (long)w * w_stride;
  const float* Bh = bhh + (long)w * b_stride;

  __half2 wr[64], wz[64], wn[64];
  {
    const float* pr = W + (long)j * 256 + kh * 128;
    const float* pz = W + (long)(j + 256) * 256 + kh * 128;
    const float* pn = W + (long)(j + 512) * 256 + kh * 128;
#pragma unroll
    for (int i = 0; i < 64; ++i) {
      wr[i] = __floats2half2_rn(pr[2 * i], pr[2 * i + 1]);
      wz[i] = __floats2half2_rn(pz[2 * i], pz[2 * i + 1]);
      wn[i] = __floats2half2_rn(pn[2 * i], pn[2 * i + 1]);
    }
  }
  const float br = Bh[j], bz = Bh[256 + j], bn = Bh[512 + j];

  __shared__ float  h32[2][256];
  __shared__ __half h16[2][256];
  if (kh == 0) {
    const float hv = h0 ? h0[(long)(c % h0_mod) * 256 + j] : 0.f;
    h32[0][j] = hv;
    h16[0][j] = __float2half(hv);
  }
  __syncthreads();

  const float* xrow = xg + (long)c * T * 768;
  float* yrow = ys ? ys + (long)c * T * 256 : nullptr;
  float xr = 0.f, xz = 0.f, xn = 0.f;
  if (kh == 0) { xr = xrow[j]; xz = xrow[256 + j]; xn = xrow[512 + j]; }
  int cur = 0;
  for (int t = 0; t < T; ++t) {
    // prefetch next step's input gates (hides HBM latency under the dot)
    float nxr = 0.f, nxz = 0.f, nxn = 0.f;
    if (kh == 0 && t + 1 < T) {
      const float* nx = xrow + (long)(t + 1) * 768;
      nxr = nx[j]; nxz = nx[256 + j]; nxn = nx[512 + j];
    }
    const __half2* hp = (const __half2*)&h16[cur][kh * 128];
    float sr = 0.f, sz = 0.f, sn = 0.f;
#pragma unroll
    for (int i0 = 0; i0 < 64; i0 += 8) {
      __half2 ar = __float2half2_rn(0.f);
      __half2 az = __float2half2_rn(0.f);
      __half2 an = __float2half2_rn(0.f);
#pragma unroll
      for (int i = 0; i < 8; ++i) {
        const __half2 hv = hp[i0 + i];
        ar = __hfma2(wr[i0 + i], hv, ar);
        az = __hfma2(wz[i0 + i], hv, az);
        an = __hfma2(wn[i0 + i], hv, an);
      }
      sr += __low2float(ar) + __high2float(ar);
      sz += __low2float(az) + __high2float(az);
      sn += __low2float(an) + __high2float(an);
    }
    sr += __shfl_xor(sr, 1);
    sz += __shfl_xor(sz, 1);
    sn += __shfl_xor(sn, 1);
    if (kh == 0) {
      const float rr = 1.f / (1.f + __expf(-(xr + sr + br)));
      const float zg = 1.f / (1.f + __expf(-(xz + sz + bz)));
      const float narg = xn + rr * (sn + bn);
      const float e = __expf(-2.f * fabsf(narg));
      const float nv = copysignf((1.f - e) / (1.f + e), narg);
      const float hnew = (1.f - zg) * nv + zg * h32[cur][j];
      h32[cur ^ 1][j] = hnew;
      h16[cur ^ 1][j] = __float2half(hnew);
      if (yrow) yrow[(long)t * 256 + j] = hnew;
    }
    __syncthreads();
    cur ^= 1;
    xr = nxr; xz = nxz; xn = nxn;
  }
  if (hT && kh == 0) hT[(long)c * 256 + j] = h32[cur][j];
}

// ---------------- dot-product attention ------------------------------------
__global__ __launch_bounds__(256) void k_attn(
    const float* __restrict__ q, const float* __restrict__ kv,
    float* __restrict__ out, int Q, int L)
{
  const int bq = blockIdx.x;
  const int b = bq / Q;
  const int tid = threadIdx.x;
  const int g = tid >> 3, l = tid & 7;
  __shared__ float qv[256];
  __shared__ float sc[64];
  qv[tid] = q[(long)bq * 256 + tid];
  __syncthreads();
  for (int k0 = 0; k0 < L; k0 += 32) {
    const int k = k0 + g;
    float s = 0.f;
    if (k < L) {
      const float* kr = kv + ((long)b * L + k) * 256;
      for (int d = l; d < 256; d += 8) s += qv[d] * kr[d];
    }
    s += __shfl_xor(s, 1);
    s += __shfl_xor(s, 2);
    s += __shfl_xor(s, 4);
    if (k < L && l == 0) sc[k] = s * 0.0625f;
  }
  __syncthreads();
  float m = -1e30f;
  for (int k = 0; k < L; ++k) m = fmaxf(m, sc[k]);
  float den = 0.f;
  for (int k = 0; k < L; ++k) den += __expf(sc[k] - m);
  __syncthreads();
  if (tid < L) sc[tid] = __expf(sc[tid] - m);
  __syncthreads();
  const float* kb = kv + (long)b * L * 256;
  float acc = 0.f;
  for (int k = 0; k < L; ++k) acc += sc[k] * kb[(long)k * 256 + tid];
  out[(long)bq * 256 + tid] = acc / den;
}

// ---------------- hierarchy attention weights ------------------------------
__global__ __launch_bounds__(64) void k_hier(
    const float* __restrict__ dec, const float* __restrict__ g4out,
    float* __restrict__ ahier, int Q)
{
  const int bq = blockIdx.x;
  const int b = bq / Q;
  const int l = threadIdx.x;
  float s[4] = {0.f, 0.f, 0.f, 0.f};
#pragma unroll
  for (int i = 0; i < 4; ++i) {
    const int d = l * 4 + i;
    const float qd = dec[(long)bq * 256 + d];
#pragma unroll
    for (int sg = 0; sg < 4; ++sg)
      s[sg] += qd * g4out[((long)sg * 32 + b) * 256 + d];
  }
#pragma unroll
  for (int off = 32; off >= 1; off >>= 1)
#pragma unroll
    for (int sg = 0; sg < 4; ++sg) s[sg] += __shfl_xor(s[sg], off);
  if (l == 0) {
    float m = -1e30f;
#pragma unroll
    for (int sg = 0; sg < 4; ++sg) m = fmaxf(m, s[sg] * 0.0625f);
    float e[4], den = 0.f;
#pragma unroll
    for (int sg = 0; sg < 4; ++sg) { e[sg] = __expf(s[sg] * 0.0625f - m); den += e[sg]; }
#pragma unroll
    for (int sg = 0; sg < 4; ++sg) ahier[(long)bq * 4 + sg] = e[sg] / den;
  }
}

// ---------------- row softmax * hierarchy weight ---------------------------
__global__ __launch_bounds__(64) void k_smax(
    float* __restrict__ sc, const float* __restrict__ ahier)
{
  const int id = blockIdx.x;          // s*960 + (b*30+q)
  const int s = id / 960;
  const int bq = id - s * 960;
  float* row = sc + (long)id * 300;
  const int l = threadIdx.x;
  float v[5];
  float m = -1e30f;
#pragma unroll
  for (int i = 0; i < 5; ++i) {
    const int k = l + i * 64;
    v[i] = (k < 300) ? row[k] * 0.0625f : -1e30f;
    m = fmaxf(m, v[i]);
  }
#pragma unroll
  for (int off = 32; off >= 1; off >>= 1) m = fmaxf(m, __shfl_xor(m, off));
  float den = 0.f;
#pragma unroll
  for (int i = 0; i < 5; ++i) { v[i] = __expf(v[i] - m); den += v[i]; }
#pragma unroll
  for (int off = 32; off >= 1; off >>= 1) den += __shfl_xor(den, off);
  const float w = ahier[(long)bq * 4 + s] / den;
#pragma unroll
  for (int i = 0; i < 5; ++i) {
    const int k = l + i * 64;
    if (k < 300) row[k] = v[i] * w;
  }
}

// ---------------- concat [tctx | dec | actx] -> [960][768] ------------------
__global__ __launch_bounds__(256) void k_concat(
    const float* __restrict__ a, const float* __restrict__ b,
    const float* __restrict__ c, float* __restrict__ out, int rows)
{
  const int total = rows * 768;
  for (int i = blockIdx.x * 256 + threadIdx.x; i < total; i += gridDim.x * 256) {
    const int r = i / 768, col = i - r * 768;
    float v;
    if (col < 256) v = a[(long)r * 256 + col];
    else if (col < 512) v = b[(long)r * 256 + col - 256];
    else v = c[(long)r * 256 + col - 512];
    out[i] = v;
  }
}

// ---------------------------------------------------------------------------
extern "C" void kernel_launch(void* const* d_in, const int* in_sizes, int n_in,
                              void* d_out, int out_size, void* d_ws, size_t ws_size,
                              hipStream_t stream) {
  const int*   x0      = (const int*)d_in[0];
  const int*   x1      = (const int*)d_in[1];
  const int*   x2      = (const int*)d_in[2];
  const float* adj     = (const float*)d_in[3];
  const float* emb_ast = (const float*)d_in[4];
  const float* emb_com = (const float*)d_in[5];
  const float* g1_wih  = (const float*)d_in[6];
  const float* g1_whh  = (const float*)d_in[7];
  const float* g1_bih  = (const float*)d_in[8];
  const float* g1_bhh  = (const float*)d_in[9];
  const float* g2_wih  = (const float*)d_in[10];
  const float* g2_whh  = (const float*)d_in[11];
  const float* g2_bih  = (const float*)d_in[12];
  const float* g2_bhh  = (const float*)d_in[13];
  const float* g4_wih  = (const float*)d_in[14];
  const float* g4_whh  = (const float*)d_in[15];
  const float* g4_bih  = (const float*)d_in[16];
  const float* g4_bhh  = (const float*)d_in[17];
  const float* g58_wih = (const float*)d_in[18];
  const float* g58_whh = (const float*)d_in[19];
  const float* g58_bih = (const float*)d_in[20];
  const float* g58_bhh = (const float*)d_in[21];
  const float* gcn_w   = (const float*)d_in[22];
  const float* gcn_b   = (const float*)d_in[23];
  const float* dw      = (const float*)d_in[24];
  const float* db      = (const float*)d_in[25];
  const float* lw      = (const float*)d_in[26];
  const float* lb      = (const float*)d_in[27];
  float* out = (float*)d_out;
  float* ws  = (float*)d_ws;

  // workspace layout (float offsets; bf16 buffers use half the floats)
  unsigned short* astwork_bf = (unsigned short*)ws;               // [4][32][300][300] bf16
  unsigned short* supportT   = (unsigned short*)(ws + 5760000L);  // [4][32][300][300] bf16 (transposed)
  float* g58xg   = ws + 11520000L;  // [4][32][300][768]
  float* outsb   = ws + 41011200L;  // [4][32][300][256]
  float* xg1     = ws + 50841600L;  // [32][50][768]
  float* tenc    = ws + 52070400L;  // [32][50][256]
  float* tstate  = ws + 52480000L;  // [32][256]
  float* xg2     = ws + 52488192L;  // [32][30][768]
  float* dec     = ws + 53225472L;  // [32][30][256]
  float* tctx    = ws + 53471232L;  // [32][30][256]
  float* g4xg    = ws + 53716992L;  // [4][32][768]
  float* g4out   = ws + 53815296L;  // [4][32][256]
  float* ahier   = ws + 53848064L;  // [32][30][4]
  float* actx1   = ws + 53851904L;  // [32][30][256]
  float* actx    = ws + 54097664L;  // [32][30][256]
  float* dense   = ws + 54343424L;  // [32][30][256]
  float* ctmp    = ws + 54589184L;  // [960][768] concat
  float* scbuf   = ws + 55326464L;  // [4][32][30][300]
  unsigned short* gcn_wT   = (unsigned short*)(ws + 56478464L);   // [300][300] bf16
  unsigned short* dense_bf = (unsigned short*)(ws + 56523464L);   // [960][256] bf16

  const dim3 blk(256);

  // 1) gather astwork (bf16) + transpose gcn_w (bf16)
  k_gather_ast<<<dim3(4096), blk, 0, stream>>>(emb_ast, x2, astwork_bf);
  k_twb<<<dim3(90), blk, 0, stream>>>(gcn_w, gcn_wT, 300, 300);

  // 2) GCN, 2 hops (MFMA): supportT = (X @ W)^T ; X = relu(adj @ support + b)
  for (int hop = 0; hop < 2; ++hop) {
    k_mfma<true, true, 3, false><<<dim3(3, 3, 128), blk, 0, stream>>>(
        astwork_bf, 300, 2880000, 90000,
        gcn_wT, 300, 0, 0,
        supportT, 300, 2880000, 90000,
        nullptr, 0, 300, 300, 300, 32, 1);
    k_mfma<false, true, 1, true><<<dim3(3, 3, 128), blk, 0, stream>>>(
        adj, 300, 90000, 360000,
        supportT, 300, 2880000, 90000,
        astwork_bf, 300, 2880000, 90000,
        gcn_b, 0, 300, 300, 300, 32, 1);
  }

  // 3) token encoder GRU1
  k_gemm<true, false, true, false><<<dim3(12, 25, 1), blk, 0, stream>>>(
      emb_ast, 300, 0, 0, g1_wih, 300, 0, 0, xg1, 768, 0, 0,
      g1_bih, 0, x0, 1600, 768, 300, 1, 1);
  k_gru_seq<<<dim3(32), dim3(512), 0, stream>>>(
      xg1, nullptr, 1, g1_whh, 0, 1, g1_bhh, 0, tenc, tstate, 50);

  // 4) comment decoder GRU2
  k_gemm<true, false, true, false><<<dim3(12, 15, 1), blk, 0, stream>>>(
      emb_com, 300, 0, 0, g2_wih, 300, 0, 0, xg2, 768, 0, 0,
      g2_bih, 0, x1, 960, 768, 300, 1, 1);
  k_gru_seq<<<dim3(32), dim3(512), 0, stream>>>(
      xg2, tstate, 32, g2_whh, 0, 1, g2_bhh, 0, dec, nullptr, 30);

  // 5) tcontext = dot_attn(dec, tenc)
  k_attn<<<dim3(960), blk, 0, stream>>>(dec, tenc, tctx, 30, 50);

  // 6) gru4: input gates via MFMA split-K atomic, then recurrence
  k_init_bias<<<dim3(384), blk, 0, stream>>>(g4xg, g4_bih, 128, 768);
  k_mfma<true, false, 2, false><<<dim3(6, 1, 43), blk, 0, stream>>>(
      astwork_bf, 90000, 0, 0, g4_wih, 90000, 0, 0, g4xg, 768, 0, 0,
      nullptr, 0, 128, 768, 90000, 1, 43);
  k_gru_seq<<<dim3(4), dim3(512), 0, stream>>>(
      g4xg, nullptr, 1, g4_whh, 0, 1, g4_bhh, 0, g4out, nullptr, 32);

  // 7) hierarchy attention weights
  k_hier<<<dim3(960), dim3(64), 0, stream>>>(dec, g4out, ahier, 30);

  // 8) gru5..8 input gates (MFMA) + recurrence
  k_mfma<true, false, 0, false><<<dim3(6, 75, 4), blk, 0, stream>>>(
      astwork_bf, 300, 2880000, 0, g58_wih, 300, 230400, 0,
      g58xg, 768, 7372800, 0, g58_bih, 768, 9600, 768, 300, 1, 1);
  k_gru_seq<<<dim3(128), dim3(512), 0, stream>>>(
      g58xg, tstate, 32, g58_whh, 196608, 32, g58_bhh, 768, outsb, nullptr, 300);

  // 9) node attention + hierarchical combine
  k_gemm<true, false, false, false><<<dim3(5, 1, 128), blk, 0, stream>>>(
      dec, 256, 0, 7680, outsb, 256, 2457600, 76800, scbuf, 300, 288000, 9000,
      nullptr, 0, nullptr, 30, 300, 256, 32, 1);
  k_smax<<<dim3(3840), dim3(64), 0, stream>>>(scbuf, ahier);
  hipMemsetAsync(actx1, 0, 245760 * sizeof(float), stream);
  k_gemm<false, false, false, true><<<dim3(4, 1, 128), blk, 0, stream>>>(
      scbuf, 300, 288000, 9000, outsb, 256, 2457600, 76800, actx1, 256, 0, 7680,
      nullptr, 0, nullptr, 30, 256, 300, 32, 1);

  // 10) acontext = dot_attn(dec, actx1)
  k_attn<<<dim3(960), blk, 0, stream>>>(dec, actx1, actx, 30, 30);

  // 11) concat + dense (relu) + bf16 copy
  k_concat<<<dim3(2880), blk, 0, stream>>>(tctx, dec, actx, ctmp, 960);
  k_gemm<true, true, false, false><<<dim3(4, 15, 1), blk, 0, stream>>>(
      ctmp, 768, 0, 0, dw, 768, 0, 0, dense, 256, 0, 0,
      db, 0, nullptr, 960, 256, 768, 1, 1);
  k_f2b<<<dim3(960), blk, 0, stream>>>(dense, dense_bf, 245760);

  // 12) final linear via MFMA split-K (streams lw once)
  k_init_bias<<<dim3(1250), blk, 0, stream>>>(out, lb, 32, 10000);
  k_mfma<true, false, 2, false><<<dim3(79, 1, 6), blk, 0, stream>>>(
      dense_bf, 7680, 0, 0, lw, 7680, 0, 0, out, 10000, 0, 0,
      nullptr, 0, 32, 10000, 7680, 1, 6);
}